// Round 1
// baseline (2857.512 us; speedup 1.0000x reference)
//
#include <hip/hip_runtime.h>

#define HIDDEN  64
#define T_STEPS 2048
#define N_INPUT 5
#define DT      0.1f
#define LN_EPS  1e-5f

// broadcast lane `l`'s value of v to all lanes (SGPR result -> fma scalar operand)
__device__ __forceinline__ float bcast(float v, int l) {
    return __uint_as_float(__builtin_amdgcn_readlane(__float_as_uint(v), l));
}

__device__ __forceinline__ float wave_sum(float v) {
#pragma unroll
    for (int m = 1; m < 64; m <<= 1) v += __shfl_xor(v, m, 64);
    return v;
}

__global__ __launch_bounds__(256, 4) void hlnn_main(
    const float* __restrict__ x, const float* __restrict__ W_in,
    const float* __restrict__ b_in, const float* __restrict__ tau_param,
    const float* __restrict__ W_rec, const float* __restrict__ ln1_w,
    const float* __restrict__ ln1_b, const float* __restrict__ ln2_w,
    const float* __restrict__ ln2_b, const float* __restrict__ head_W,
    const float* __restrict__ head_b, float* __restrict__ out, int B)
{
    const int lane = threadIdx.x & 63;
    const int wav  = threadIdx.x >> 6;
    const int b    = blockIdx.x * 4 + wav;   // one wave per batch row

    // ---- per-lane constants (lane j owns hidden unit j) ----
    float wcol[HIDDEN];                       // W_rec[:, lane] in VGPRs
#pragma unroll
    for (int i = 0; i < HIDDEN; ++i) wcol[i] = W_rec[i * HIDDEN + lane];

    float win[N_INPUT];                       // W_in[:, lane]
#pragma unroll
    for (int s = 0; s < N_INPUT; ++s) win[s] = W_in[s * HIDDEN + lane];

    const float binv = b_in[lane];
    const float l1w  = ln1_w[lane], l1b = ln1_b[lane];
    const float tau  = log1pf(expf(tau_param[lane]));   // softplus
    const float decay = 1.0f - DT / tau;                // h*(1 - dt/tau) + dt*f

    float h = 0.0f;
    const float* xb = x + (size_t)b * (T_STEPS * N_INPUT);

    float xs[N_INPUT];
#pragma unroll
    for (int s = 0; s < N_INPUT; ++s) xs[s] = xb[s];

    for (int t = 0; t < T_STEPS; ++t) {
        // software-prefetch next step's 5 input scalars
        const int tn = (t + 1 < T_STEPS) ? (t + 1) : t;
        float xn[N_INPUT];
#pragma unroll
        for (int s = 0; s < N_INPUT; ++s) xn[s] = xb[(size_t)tn * N_INPUT + s];

        // pre[j] = b_in[j] + x_t . W_in[:,j] + sum_i h[i] * W_rec[i][j]
        float p0 = binv, p1 = 0.0f, p2 = 0.0f, p3 = 0.0f;
#pragma unroll
        for (int s = 0; s < N_INPUT; ++s) p0 = fmaf(xs[s], win[s], p0);
#pragma unroll
        for (int i = 0; i < HIDDEN; i += 4) {
            p0 = fmaf(bcast(h, i + 0), wcol[i + 0], p0);
            p1 = fmaf(bcast(h, i + 1), wcol[i + 1], p1);
            p2 = fmaf(bcast(h, i + 2), wcol[i + 2], p2);
            p3 = fmaf(bcast(h, i + 3), wcol[i + 3], p3);
        }
        const float pre = (p0 + p1) + (p2 + p3);

        // LayerNorm over the wave (64 hidden units), single-pass sum/sumsq
        float sum = pre, sumsq = pre * pre;
#pragma unroll
        for (int m = 1; m < 64; m <<= 1) {
            sum   += __shfl_xor(sum,   m, 64);
            sumsq += __shfl_xor(sumsq, m, 64);
        }
        const float mu   = sum * (1.0f / 64.0f);
        float var        = fmaf(mu, -mu, sumsq * (1.0f / 64.0f));
        var              = fmaxf(var, 0.0f);
        const float rstd = rsqrtf(var + LN_EPS);

        const float f = tanhf(fmaf((pre - mu) * rstd, l1w, l1b));
        h = fmaf(decay, h, DT * f);
        h = fminf(fmaxf(h, -10.0f), 10.0f);

#pragma unroll
        for (int s = 0; s < N_INPUT; ++s) xs[s] = xn[s];
    }

    // ---- epilogue: LN2 + 5x4 heads ----
    float sum = h, sumsq = h * h;
#pragma unroll
    for (int m = 1; m < 64; m <<= 1) {
        sum   += __shfl_xor(sum,   m, 64);
        sumsq += __shfl_xor(sumsq, m, 64);
    }
    const float mu   = sum * (1.0f / 64.0f);
    float var        = fmaf(mu, -mu, sumsq * (1.0f / 64.0f));
    var              = fmaxf(var, 0.0f);
    const float rstd = rsqrtf(var + LN_EPS);
    const float hn   = fmaf((h - mu) * rstd, ln2_w[lane], ln2_b[lane]);

    float myout = 0.0f;
#pragma unroll
    for (int o = 0; o < 20; ++o) {
        float p = hn * head_W[o * HIDDEN + lane];
        p = wave_sum(p);
        if (lane == o) myout = p + head_b[o];
    }
    if (lane < 20) {
        const int k = lane >> 2, a = lane & 3;   // out[k][b][a], shape (5,B,4)
        out[(size_t)k * B * 4 + (size_t)b * 4 + a] = myout;
    }
}

extern "C" void kernel_launch(void* const* d_in, const int* in_sizes, int n_in,
                              void* d_out, int out_size, void* d_ws, size_t ws_size,
                              hipStream_t stream) {
    const float* x         = (const float*)d_in[0];
    const float* W_in      = (const float*)d_in[1];
    const float* b_in      = (const float*)d_in[2];
    const float* tau_param = (const float*)d_in[3];
    const float* W_rec     = (const float*)d_in[4];
    const float* ln1_w     = (const float*)d_in[5];
    const float* ln1_b     = (const float*)d_in[6];
    const float* ln2_w     = (const float*)d_in[7];
    const float* ln2_b     = (const float*)d_in[8];
    const float* head_W    = (const float*)d_in[9];
    const float* head_b    = (const float*)d_in[10];

    const int B = in_sizes[0] / (T_STEPS * N_INPUT);   // 4096
    dim3 grid(B / 4), block(256);                      // one wave per row
    hipLaunchKernelGGL(hlnn_main, grid, block, 0, stream,
                       x, W_in, b_in, tau_param, W_rec, ln1_w, ln1_b,
                       ln2_w, ln2_b, head_W, head_b, (float*)d_out, B);
}

// Round 2
// 2692.459 us; speedup vs baseline: 1.0613x; 1.0613x over previous
//
#include <hip/hip_runtime.h>

#define HIDDEN  64
#define T_STEPS 2048
#define N_INPUT 5
#define DT      0.1f
#define LN_EPS  1e-5f

// broadcast lane `l`'s value of v to all lanes (SGPR result -> fmac scalar operand)
__device__ __forceinline__ float bcast(float v, int l) {
    return __uint_as_float(__builtin_amdgcn_readlane(__float_as_uint(v), l));
}

// single-instruction xor-swizzle within 32-lane halves (BitMode: xor<<10 | 0x1F)
template <int XMASK>
__device__ __forceinline__ float swz_xor(float v) {
    return __uint_as_float(
        __builtin_amdgcn_ds_swizzle(__float_as_uint(v), (XMASK << 10) | 0x1F));
}

// cross-half exchange (lane ^ 32); addr32 = ((lane^32)<<2) hoisted by caller
__device__ __forceinline__ float bperm(int addr32, float v) {
    return __uint_as_float(__builtin_amdgcn_ds_bpermute(addr32, __float_as_uint(v)));
}

// fast tanh: (e-1)/(e+1), e = 2^(2*log2e*y); y pre-clamped so e is finite
__device__ __forceinline__ float fast_tanh(float y) {
    y = fminf(fmaxf(y, -15.0f), 15.0f);
    const float e = exp2f(y * 2.885390081777927f);  // 2*log2(e)
    return (e - 1.0f) * __frcp_rn(e + 1.0f);
}

__global__ __launch_bounds__(256, 4) void hlnn_main(
    const float* __restrict__ x, const float* __restrict__ W_in,
    const float* __restrict__ b_in, const float* __restrict__ tau_param,
    const float* __restrict__ W_rec, const float* __restrict__ ln1_w,
    const float* __restrict__ ln1_b, const float* __restrict__ ln2_w,
    const float* __restrict__ ln2_b, const float* __restrict__ head_W,
    const float* __restrict__ head_b, float* __restrict__ out, int B)
{
    const int lane = threadIdx.x & 63;
    const int wav  = threadIdx.x >> 6;
    const int b    = blockIdx.x * 4 + wav;         // one wave per batch row
    const int addr32 = ((lane ^ 32) & 63) << 2;    // hoisted bpermute address

    // ---- per-lane constants (lane j owns hidden unit j) ----
    float wcol[HIDDEN];                            // W_rec[:, lane] in VGPRs
#pragma unroll
    for (int i = 0; i < HIDDEN; ++i) wcol[i] = W_rec[i * HIDDEN + lane];

    float win[N_INPUT];                            // W_in[:, lane]
#pragma unroll
    for (int s = 0; s < N_INPUT; ++s) win[s] = W_in[s * HIDDEN + lane];

    const float binv = b_in[lane];
    const float l1w  = ln1_w[lane], l1b = ln1_b[lane];
    const float tau  = log1pf(expf(tau_param[lane]));   // softplus
    const float decay = 1.0f - DT / tau;                // h*(1 - dt/tau) + dt*f

    float h = 0.0f;
    const float* xb = x + (size_t)b * (T_STEPS * N_INPUT);

    float xs[N_INPUT];
#pragma unroll
    for (int s = 0; s < N_INPUT; ++s) xs[s] = xb[s];

#pragma unroll 2
    for (int t = 0; t < T_STEPS; ++t) {
        // prefetch next step's 5 input scalars (wave-uniform)
        const int tn = (t + 1 < T_STEPS) ? (t + 1) : t;
        float xn[N_INPUT];
#pragma unroll
        for (int s = 0; s < N_INPUT; ++s) xn[s] = xb[(size_t)tn * N_INPUT + s];

        // pre[j] = b_in[j] + x_t . W_in[:,j] + sum_i h[i] * W_rec[i][j]
        float p0 = binv, p1 = 0.0f, p2 = 0.0f, p3 = 0.0f;
#pragma unroll
        for (int s = 0; s < N_INPUT; ++s) p0 = fmaf(xs[s], win[s], p0);
#pragma unroll
        for (int i = 0; i < HIDDEN; i += 4) {
            p0 = fmaf(bcast(h, i + 0), wcol[i + 0], p0);
            p1 = fmaf(bcast(h, i + 1), wcol[i + 1], p1);
            p2 = fmaf(bcast(h, i + 2), wcol[i + 2], p2);
            p3 = fmaf(bcast(h, i + 3), wcol[i + 3], p3);
        }
        const float pre = (p0 + p1) + (p2 + p3);

        // LayerNorm reduction: 5 xor-swizzles within halves + 1 cross-half bpermute
        float sum = pre, sumsq = pre * pre;
        sum += swz_xor<1>(sum);   sumsq += swz_xor<1>(sumsq);
        sum += swz_xor<2>(sum);   sumsq += swz_xor<2>(sumsq);
        sum += swz_xor<4>(sum);   sumsq += swz_xor<4>(sumsq);
        sum += swz_xor<8>(sum);   sumsq += swz_xor<8>(sumsq);
        sum += swz_xor<16>(sum);  sumsq += swz_xor<16>(sumsq);
        sum += bperm(addr32, sum);
        sumsq += bperm(addr32, sumsq);

        const float mu   = sum * (1.0f / 64.0f);
        float var        = fmaf(mu, -mu, sumsq * (1.0f / 64.0f));
        var              = fmaxf(var, 0.0f);
        const float rstd = rsqrtf(var + LN_EPS);

        const float f = fast_tanh(fmaf((pre - mu) * rstd, l1w, l1b));
        h = fmaf(decay, h, DT * f);
        h = fminf(fmaxf(h, -10.0f), 10.0f);

#pragma unroll
        for (int s = 0; s < N_INPUT; ++s) xs[s] = xn[s];
    }

    // ---- epilogue: LN2 + 5x4 heads (once; cost negligible) ----
    float sum = h, sumsq = h * h;
    sum += swz_xor<1>(sum);   sumsq += swz_xor<1>(sumsq);
    sum += swz_xor<2>(sum);   sumsq += swz_xor<2>(sumsq);
    sum += swz_xor<4>(sum);   sumsq += swz_xor<4>(sumsq);
    sum += swz_xor<8>(sum);   sumsq += swz_xor<8>(sumsq);
    sum += swz_xor<16>(sum);  sumsq += swz_xor<16>(sumsq);
    sum += bperm(addr32, sum);
    sumsq += bperm(addr32, sumsq);

    const float mu   = sum * (1.0f / 64.0f);
    float var        = fmaf(mu, -mu, sumsq * (1.0f / 64.0f));
    var              = fmaxf(var, 0.0f);
    const float rstd = rsqrtf(var + LN_EPS);
    const float hn   = fmaf((h - mu) * rstd, ln2_w[lane], ln2_b[lane]);

    float myout = 0.0f;
#pragma unroll
    for (int o = 0; o < 20; ++o) {
        float p = hn * head_W[o * HIDDEN + lane];
        p += swz_xor<1>(p);
        p += swz_xor<2>(p);
        p += swz_xor<4>(p);
        p += swz_xor<8>(p);
        p += swz_xor<16>(p);
        p += bperm(addr32, p);
        if (lane == o) myout = p + head_b[o];
    }
    if (lane < 20) {
        const int k = lane >> 2, a = lane & 3;     // out[k][b][a], shape (5,B,4)
        out[(size_t)k * B * 4 + (size_t)b * 4 + a] = myout;
    }
}

extern "C" void kernel_launch(void* const* d_in, const int* in_sizes, int n_in,
                              void* d_out, int out_size, void* d_ws, size_t ws_size,
                              hipStream_t stream) {
    const float* x         = (const float*)d_in[0];
    const float* W_in      = (const float*)d_in[1];
    const float* b_in      = (const float*)d_in[2];
    const float* tau_param = (const float*)d_in[3];
    const float* W_rec     = (const float*)d_in[4];
    const float* ln1_w     = (const float*)d_in[5];
    const float* ln1_b     = (const float*)d_in[6];
    const float* ln2_w     = (const float*)d_in[7];
    const float* ln2_b     = (const float*)d_in[8];
    const float* head_W    = (const float*)d_in[9];
    const float* head_b    = (const float*)d_in[10];

    const int B = in_sizes[0] / (T_STEPS * N_INPUT);   // 4096
    dim3 grid(B / 4), block(256);                      // one wave per row
    hipLaunchKernelGGL(hlnn_main, grid, block, 0, stream,
                       x, W_in, b_in, tau_param, W_rec, ln1_w, ln1_b,
                       ln2_w, ln2_b, head_W, head_b, (float*)d_out, B);
}